// Round 9
// baseline (226.228 us; speedup 1.0000x reference)
//
#include <hip/hip_runtime.h>
#include <hip/hip_bf16.h>
#include <math.h>

// DiT block. b=64, n=512 (8x8x8), d=128, H=4, dk=32.
// Round 9: k_norm_qkv register-LN + direct-global bf16 weight frags (k_prep
// pre-casts weights once). Kills the 3.57M bank conflicts + 87KB LDS.
// ws layout (bytes):
//   Qb  bf16 [64][4][512][32]   8 MB  (pre-scaled by log2e/sqrt(32))
//   Kb  bf16 [64][4][512][32]   8 MB
//   Vtb bf16 [64][4][32][512]   8 MB  (transposed [dk][n])
//   Ob  bf16 [64][512][128]     8 MB  (i-ordered: i = k*4+h, permute pre-applied)
//   mods f32 [64][6][128]      192 KB @ 33554432
//   cT  bf16 [3][128][128]      96 KB @ 33751040  (W^T per phase: [c][d])
//   owT bf16 [128][128]         32 KB @ 33849344  (owT[c][i] = ow[i][c])
// mods slots per b: 0=alpha1(g1), 1=gamma1(be1), 2=beta1(al1),
//                   3=alpha2(g2), 4=gamma2(be2), 5=beta2(al2)   (bug-faithful)

#define NB 64

typedef __attribute__((ext_vector_type(8))) short bf16x8;
typedef __attribute__((ext_vector_type(4))) float f32x4;

__device__ __forceinline__ float silu_f(float x) { return x / (1.0f + __expf(-x)); }
__device__ __forceinline__ unsigned short f2bf(float x) {
    __hip_bfloat16 h = __float2bfloat16(x);
    return *reinterpret_cast<unsigned short*>(&h);
}

// ---------------- K0: weight pre-cast ----------------
// grid 256 x 256 threads = 65536 = 3*16384 (qkv) + 16384 (ow)
__global__ void __launch_bounds__(256) k_prep(
    const float* __restrict__ qw, const float* __restrict__ kw,
    const float* __restrict__ vw, const float* __restrict__ ow,
    unsigned short* __restrict__ cT, unsigned short* __restrict__ owT)
{
    int idx = blockIdx.x*256 + threadIdx.x;
    if (idx < 49152) {
        int ph = idx >> 14, r = idx & 16383, c = r >> 7, d = r & 127;
        int h = c >> 5, kk = c & 31;
        const float* wp = ph==0 ? qw : (ph==1 ? kw : vw);
        cT[idx] = f2bf(wp[h*4096 + d*32 + kk]);
    } else {
        int r = idx - 49152, c = r >> 7, i = r & 127;
        owT[r] = f2bf(ow[i*128 + c]);
    }
}

// ---------------- K1: cond MLPs ----------------
__global__ void __launch_bounds__(128) k_cond(
    const float* __restrict__ nodes, const float* __restrict__ tv,
    const float* __restrict__ w10, const float* __restrict__ b10,
    const float* __restrict__ w20, const float* __restrict__ b20,
    const float* __restrict__ w30, const float* __restrict__ b30,
    const float* __restrict__ w11, const float* __restrict__ b11,
    const float* __restrict__ w21, const float* __restrict__ b21,
    const float* __restrict__ w31, const float* __restrict__ b31,
    const float* __restrict__ w12, const float* __restrict__ b12,
    const float* __restrict__ w22, const float* __restrict__ b22,
    const float* __restrict__ w32, const float* __restrict__ b32,
    const float* __restrict__ w13, const float* __restrict__ b13,
    const float* __restrict__ w23, const float* __restrict__ b23,
    const float* __restrict__ w33, const float* __restrict__ b33,
    float* __restrict__ mods)
{
    int blk = blockIdx.x;
    int b = blk >> 2, m = blk & 3;
    const float* W1 = m==0?w10 : m==1?w11 : m==2?w12 : w13;
    const float* B1 = m==0?b10 : m==1?b11 : m==2?b12 : b13;
    const float* W2 = m==0?w20 : m==1?w21 : m==2?w22 : w23;
    const float* B2 = m==0?b20 : m==1?b21 : m==2?b22 : b23;
    const float* W3 = m==0?w30 : m==1?w31 : m==2?w32 : w33;
    const float* B3 = m==0?b30 : m==1?b31 : m==2?b32 : b33;
    int dout256 = (m == 0 || m == 2);
    int slot = (m==0)?0 : (m==1)?2 : (m==2)?3 : 5;

    __shared__ float xs[128], h1[128], h2[128];
    int t = threadIdx.x;
    xs[t] = nodes[b*128 + t] + tv[b];
    __syncthreads();

    float acc = B1[t];
    for (int i = 0; i < 128; i++) acc += xs[i] * W1[i*128 + t];
    h1[t] = silu_f(acc);
    __syncthreads();

    acc = B2[t];
    for (int i = 0; i < 128; i++) acc += h1[i] * W2[i*128 + t];
    h2[t] = silu_f(acc);
    __syncthreads();

    if (dout256) {
        float a0 = B3[t], a1 = B3[t + 128];
        for (int i = 0; i < 128; i++) {
            float h = h2[i];
            a0 += h * W3[i*256 + t];
            a1 += h * W3[i*256 + t + 128];
        }
        mods[((size_t)b*6 + slot    )*128 + t] = a0;
        mods[((size_t)b*6 + slot + 1)*128 + t] = a1;
    } else {
        float a0 = B3[t];
        for (int i = 0; i < 128; i++) a0 += h2[i] * W3[i*128 + t];
        mods[((size_t)b*6 + slot)*128 + t] = a0;
    }
}

// ---------------- K2: register-LN + modulate + MFMA QKV (global W frags) ----
// grid = NB*8 blocks (b, 64-row tile), 256 threads (4 waves; wave = m-tile)
__global__ void __launch_bounds__(256, 4) k_norm_qkv(
    const float* __restrict__ latent, const float* __restrict__ mods,
    const unsigned short* __restrict__ cT,
    const float* __restrict__ qb, const float* __restrict__ kb, const float* __restrict__ vb,
    unsigned short* __restrict__ Qb, unsigned short* __restrict__ Kb,
    unsigned short* __restrict__ Vtb)
{
    __shared__ unsigned short xb[64*136];   // normalized bf16 [n][d]; reused as V staging [128][68]

    int blk = blockIdx.x;
    int b = blk >> 3, n0 = (blk & 7) * 64;
    int t = threadIdx.x;
    int j = t >> 2, sub = t & 3;            // row j (0..63), d-quarter sub

    // --- load 32 raw f32 for (row n0+j, d = sub*32 + i) ---
    const float* lp = latent + (size_t)b*65536 + n0 + j;
    float lat[32];
    #pragma unroll
    for (int i = 0; i < 32; i++)
        lat[i] = lp[(size_t)(sub*32 + i)*512];

    // --- LN stats (ddof=1) via 2 shfl over the 4 subs of this row ---
    float s = 0.f, ss = 0.f;
    #pragma unroll
    for (int i = 0; i < 32; i++) { s += lat[i]; ss += lat[i]*lat[i]; }
    s += __shfl_xor(s, 1); ss += __shfl_xor(ss, 1);
    s += __shfl_xor(s, 2); ss += __shfl_xor(ss, 2);
    float mean = s * (1.0f/128.0f);
    float var = (ss - 128.0f*mean*mean) * (1.0f/127.0f);
    var = var < 0.f ? 0.f : var;
    float sd = sqrtf(var);
    float rstd = (sd == 0.f) ? 1.f : 1.f/sd;

    // --- modulate (gamma1=be1, beta1=al1 : bug-faithful), pack bf16 pairs ---
    const float* g1p  = mods + ((size_t)b*6 + 1)*128 + sub*32;
    const float* be1p = mods + ((size_t)b*6 + 2)*128 + sub*32;
    unsigned int* xbw = (unsigned int*)xb + j*68 + sub*16;
    #pragma unroll
    for (int i2 = 0; i2 < 16; i2++) {
        float v0 = g1p[2*i2]   * ((lat[2*i2]   - mean)*rstd) + be1p[2*i2];
        float v1 = g1p[2*i2+1] * ((lat[2*i2+1] - mean)*rstd) + be1p[2*i2+1];
        xbw[i2] = (unsigned)f2bf(v0) | ((unsigned)f2bf(v1) << 16);
    }
    __syncthreads();

    int w = t >> 6, lane = t & 63, lo = lane & 15, hi = lane >> 4;
    bf16x8 af[4];
    #pragma unroll
    for (int kc = 0; kc < 4; kc++)
        af[kc] = *(const bf16x8*)(xb + (w*16 + lo)*136 + kc*32 + hi*8);
    __syncthreads();   // all af read before xb is reused for V staging

    const f32x4 zero = {0.f, 0.f, 0.f, 0.f};
    const float qscale = 0.17677669529663687f * 1.4426950408889634f; // 1/sqrt(32)*log2e

    #pragma unroll 1
    for (int ph = 0; ph < 3; ph++) {
        const unsigned short* ct = cT + ph*16384;
        for (int nt = 0; nt < 8; nt++) {
            f32x4 acc = zero;
            #pragma unroll
            for (int kc = 0; kc < 4; kc++) {
                bf16x8 bf = *(const bf16x8*)(ct + (nt*16 + lo)*128 + kc*32 + hi*8);
                acc = __builtin_amdgcn_mfma_f32_16x16x32_bf16(af[kc], bf, acc, 0, 0, 0);
            }
            int c = nt*16 + lo, h = c >> 5, kk = c & 31;
            size_t bh = (size_t)(b*4 + h);
            if (ph == 0) {
                float bias = qb[c];
                #pragma unroll
                for (int jj = 0; jj < 4; jj++) {
                    int n = n0 + w*16 + hi*4 + jj;
                    Qb[(bh*512 + n)*32 + kk] = f2bf((acc[jj] + bias) * qscale);
                }
            } else if (ph == 1) {
                float bias = kb[c];
                #pragma unroll
                for (int jj = 0; jj < 4; jj++) {
                    int n = n0 + w*16 + hi*4 + jj;
                    Kb[(bh*512 + n)*32 + kk] = f2bf(acc[jj] + bias);
                }
            } else {
                float bias = vb[c];
                #pragma unroll
                for (int jj = 0; jj < 4; jj++) {
                    int nl = w*16 + hi*4 + jj;
                    xb[c*68 + nl] = f2bf(acc[jj] + bias);
                }
            }
        }
    }
    __syncthreads();
    // V write-out: Vtb[bh][kk][n0..n0+63], coalesced 64-wide
    for (int idx = t; idx < 8192; idx += 256) {
        int c = idx >> 6, jj = idx & 63;
        int h = c >> 5, kk = c & 31;
        size_t bh = (size_t)(b*4 + h);
        Vtb[(bh*32 + kk)*512 + n0 + jj] = xb[c*68 + jj];
    }
}

// ---------------- K3: MFMA attention, online-softmax chunked ----------------
// grid = NB*4*2 blocks (bh, q-half), 512 threads (8 waves).
__global__ void __launch_bounds__(512, 4) k_attn(
    const unsigned short* __restrict__ Qb, const unsigned short* __restrict__ Kb,
    const unsigned short* __restrict__ Vtb, unsigned short* __restrict__ Ob)
{
    __shared__ unsigned short KsS[512*32];   // [key][dk] linear
    __shared__ unsigned short VsS[32*512];   // [dk][key], col ^= (row&7)<<3

    int blk = blockIdx.x;
    int bh = blk >> 1, qhalf = blk & 1;
    int t = threadIdx.x;

    const unsigned short* kgp = Kb + (size_t)bh*512*32;
    const unsigned short* vgp = Vtb + (size_t)bh*32*512;
    for (int idx = t; idx < 2048; idx += 512)
        *(bf16x8*)(KsS + idx*8) = *(const bf16x8*)(kgp + idx*8);
    for (int idx = t; idx < 2048; idx += 512) {
        int r = idx >> 6, cch = idx & 63;
        *(bf16x8*)(VsS + r*512 + ((cch*8) ^ ((r&7)<<3))) =
            *(const bf16x8*)(vgp + r*512 + cch*8);
    }
    __syncthreads();

    int w = t >> 6, lane = t & 63, lo = lane & 15, hi = lane >> 4;
    const unsigned short* qbase = Qb + (size_t)bh*512*32;
    const f32x4 zero = {0.f, 0.f, 0.f, 0.f};
    int b = bh >> 2, h = bh & 3;

    const unsigned short* Vl0 = VsS + lo*512;
    const unsigned short* Vl1 = VsS + (16 + lo)*512;
    int swz = (lo & 7) << 3;
    int srcA = lo + 32*(hi & 1);

    for (int qt = 0; qt < 2; ++qt) {
        int q0 = qhalf*256 + w*32 + qt*16;
        bf16x8 qa = *(const bf16x8*)(qbase + (size_t)(q0 + lo)*32 + hi*8);

        float m = -1e30f, sum = 0.f;
        f32x4 oa = zero, ob = zero;

        #pragma unroll 1
        for (int ch = 0; ch < 4; ++ch) {
            f32x4 s8[8];
            #pragma unroll
            for (int kt = 0; kt < 8; ++kt) {
                bf16x8 kf = *(const bf16x8*)(KsS + ((ch*8 + kt)*16 + lo)*32 + hi*8);
                s8[kt] = __builtin_amdgcn_mfma_f32_16x16x32_bf16(kf, qa, zero, 0, 0, 0);
            }

            float cm = -1e30f;
            #pragma unroll
            for (int kt = 0; kt < 8; ++kt)
                cm = fmaxf(cm, fmaxf(fmaxf(s8[kt][0], s8[kt][1]), fmaxf(s8[kt][2], s8[kt][3])));
            cm = fmaxf(cm, __shfl_xor(cm, 16));
            cm = fmaxf(cm, __shfl_xor(cm, 32));
            float nm = fmaxf(m, cm);
            float sc = __builtin_amdgcn_exp2f(m - nm);
            sum *= sc;
            #pragma unroll
            for (int jj = 0; jj < 4; ++jj) { oa[jj] *= sc; ob[jj] *= sc; }
            m = nm;

            unsigned pw0c[8], pw1c[8];
            #pragma unroll
            for (int kt = 0; kt < 8; ++kt) {
                float p0 = __builtin_amdgcn_exp2f(s8[kt][0] - nm);
                float p1 = __builtin_amdgcn_exp2f(s8[kt][1] - nm);
                float p2 = __builtin_amdgcn_exp2f(s8[kt][2] - nm);
                float p3 = __builtin_amdgcn_exp2f(s8[kt][3] - nm);
                sum += (p0 + p1) + (p2 + p3);
                pw0c[kt] = (unsigned)f2bf(p0) | ((unsigned)f2bf(p1) << 16);
                pw1c[kt] = (unsigned)f2bf(p2) | ((unsigned)f2bf(p3) << 16);
            }

            #pragma unroll
            for (int kt2 = 0; kt2 < 4; ++kt2) {
                unsigned e0 = pw0c[2*kt2],     e1 = pw1c[2*kt2];
                unsigned o0 = pw0c[2*kt2 + 1], o1 = pw1c[2*kt2 + 1];
                unsigned ae0 = (unsigned)__shfl((int)e0, srcA, 64);
                unsigned ae1 = (unsigned)__shfl((int)e1, srcA, 64);
                unsigned ao0 = (unsigned)__shfl((int)o0, srcA, 64);
                unsigned ao1 = (unsigned)__shfl((int)o1, srcA, 64);
                unsigned be0 = (unsigned)__shfl((int)e0, srcA + 16, 64);
                unsigned be1 = (unsigned)__shfl((int)e1, srcA + 16, 64);
                unsigned bo0 = (unsigned)__shfl((int)o0, srcA + 16, 64);
                unsigned bo1 = (unsigned)__shfl((int)o1, srcA + 16, 64);
                union { unsigned u[4]; bf16x8 v; } pb;
                pb.u[0] = (hi < 2) ? ae0 : ao0;
                pb.u[1] = (hi < 2) ? ae1 : ao1;
                pb.u[2] = (hi < 2) ? be0 : bo0;
                pb.u[3] = (hi < 2) ? be1 : bo1;
                int off = (((ch*4 + kt2)*32) + hi*8) ^ swz;
                bf16x8 v0 = *(const bf16x8*)(Vl0 + off);
                bf16x8 v1 = *(const bf16x8*)(Vl1 + off);
                oa = __builtin_amdgcn_mfma_f32_16x16x32_bf16(v0, pb.v, oa, 0, 0, 0);
                ob = __builtin_amdgcn_mfma_f32_16x16x32_bf16(v1, pb.v, ob, 0, 0, 0);
            }
        }

        sum += __shfl_xor(sum, 16);
        sum += __shfl_xor(sum, 32);

        float inv = 1.f / sum;
        unsigned short* op = Ob + ((size_t)(b*512 + q0 + lo))*128 + h;
        #pragma unroll
        for (int jj = 0; jj < 4; ++jj) {
            op[(hi*4 + jj)*4]       = f2bf(oa[jj] * inv);
            op[(16 + hi*4 + jj)*4]  = f2bf(ob[jj] * inv);
        }
    }
}

// ---------------- K4: MFMA O@ow (global W frags) + residual + LN2 + residual ----
// grid = NB*8 blocks, 256 threads (4 waves; wave = m-tile)
__global__ void __launch_bounds__(256, 4) k_out(
    const float* __restrict__ latent, const unsigned short* __restrict__ Ob,
    const unsigned short* __restrict__ owT, const float* __restrict__ mods,
    float* __restrict__ outp)
{
    __shared__ float xs[64*129];
    __shared__ float a1s[128], a2s[128], g2s[128], b2s[128];
    __shared__ float mean_s[64], rstd_s[64];

    int blk = blockIdx.x;
    int b = blk >> 3, n0 = (blk & 7) * 64;
    int t = threadIdx.x;

    if (t < 128) {
        a1s[t] = mods[((size_t)b*6 + 0)*128 + t];  // alpha1 = g1 (bug)
        a2s[t] = mods[((size_t)b*6 + 3)*128 + t];  // alpha2 = g2 (bug)
        g2s[t] = mods[((size_t)b*6 + 4)*128 + t];  // gamma2 = be2 (bug)
        b2s[t] = mods[((size_t)b*6 + 5)*128 + t];  // beta2  = al2 (bug)
    }
    const float* lp = latent + (size_t)b*65536 + n0;
    for (int idx = t; idx < 8192; idx += 256) {
        int d = idx >> 6, jj = idx & 63;
        xs[jj*129 + d] = lp[(size_t)d*512 + jj];
    }
    __syncthreads();

    int w = t >> 6, lane = t & 63, lo = lane & 15, hi = lane >> 4;

    const unsigned short* arow = Ob + ((size_t)(b*512 + n0 + w*16 + lo))*128;
    bf16x8 af[4];
    #pragma unroll
    for (int kc = 0; kc < 4; kc++)
        af[kc] = *(const bf16x8*)(arow + kc*32 + hi*8);

    const f32x4 zero = {0.f, 0.f, 0.f, 0.f};
    for (int nt = 0; nt < 8; nt++) {
        f32x4 acc = zero;
        #pragma unroll
        for (int kc = 0; kc < 4; kc++) {
            bf16x8 bf = *(const bf16x8*)(owT + (nt*16 + lo)*128 + kc*32 + hi*8);
            acc = __builtin_amdgcn_mfma_f32_16x16x32_bf16(af[kc], bf, acc, 0, 0, 0);
        }
        int c = nt*16 + lo;
        #pragma unroll
        for (int jj = 0; jj < 4; jj++) {
            int nl = w*16 + hi*4 + jj;
            xs[nl*129 + c] += a1s[c] * acc[jj];
        }
    }
    __syncthreads();

    {
        int row = t >> 2, sub = t & 3;
        float s = 0.f, ss = 0.f;
        const float* xr = &xs[row*129 + sub*32];
        #pragma unroll
        for (int i = 0; i < 32; i++) { float v = xr[i]; s += v; ss += v*v; }
        s += __shfl_xor(s, 1); ss += __shfl_xor(ss, 1);
        s += __shfl_xor(s, 2); ss += __shfl_xor(ss, 2);
        float mean = s * (1.0f/128.0f);
        float var = (ss - 128.0f*mean*mean) * (1.0f/127.0f);
        var = var < 0.f ? 0.f : var;
        float sd = sqrtf(var);
        mean_s[row] = mean;
        rstd_s[row] = (sd == 0.f) ? 1.f : 1.f/sd;
    }
    __syncthreads();

    float* outb = outp + (size_t)b*65536 + n0;
    for (int idx = t; idx < 8192; idx += 256) {
        int d = idx >> 6, jj = idx & 63;
        float v = xs[jj*129 + d];
        float nv = (v - mean_s[jj]) * rstd_s[jj];
        outb[(size_t)d*512 + jj] = v + a2s[d]*(g2s[d]*nv + b2s[d]);
    }
}

extern "C" void kernel_launch(void* const* d_in, const int* in_sizes, int n_in,
                              void* d_out, int out_size, void* d_ws, size_t ws_size,
                              hipStream_t stream) {
    const float* latent = (const float*)d_in[0];
    const float* nodes  = (const float*)d_in[1];
    const float* tv     = (const float*)d_in[2];
    const float* qw     = (const float*)d_in[3];
    const float* kw     = (const float*)d_in[4];
    const float* vw     = (const float*)d_in[5];
    const float* qb     = (const float*)d_in[6];
    const float* kb     = (const float*)d_in[7];
    const float* vb     = (const float*)d_in[8];
    const float* owp    = (const float*)d_in[9];

    const float* mw[24];
    for (int i = 0; i < 24; i++) mw[i] = (const float*)d_in[10 + i];

    char* wsb = (char*)d_ws;
    unsigned short* Qb  = (unsigned short*)(wsb);
    unsigned short* Kb  = (unsigned short*)(wsb + 8388608);
    unsigned short* Vtb = (unsigned short*)(wsb + 16777216);
    unsigned short* Ob  = (unsigned short*)(wsb + 25165824);
    float* mods         = (float*)(wsb + 33554432);
    unsigned short* cT  = (unsigned short*)(wsb + 33751040);
    unsigned short* owT = (unsigned short*)(wsb + 33849344);

    float* outp = (float*)d_out;

    k_prep<<<dim3(256), dim3(256), 0, stream>>>(qw, kw, vw, owp, cT, owT);

    k_cond<<<dim3(NB*4), dim3(128), 0, stream>>>(
        nodes, tv,
        mw[0], mw[1], mw[2], mw[3], mw[4], mw[5],
        mw[6], mw[7], mw[8], mw[9], mw[10], mw[11],
        mw[12], mw[13], mw[14], mw[15], mw[16], mw[17],
        mw[18], mw[19], mw[20], mw[21], mw[22], mw[23],
        mods);

    k_norm_qkv<<<dim3(NB*8), dim3(256), 0, stream>>>(
        latent, mods, cT, qb, kb, vb, Qb, Kb, Vtb);

    k_attn<<<dim3(NB*4*2), dim3(512), 0, stream>>>(Qb, Kb, Vtb, Ob);

    k_out<<<dim3(NB*8), dim3(256), 0, stream>>>(latent, Ob, owT, mods, outp);
}

// Round 10
// 200.841 us; speedup vs baseline: 1.1264x; 1.1264x over previous
//
#include <hip/hip_runtime.h>
#include <hip/hip_bf16.h>
#include <math.h>

// DiT block. b=64, n=512 (8x8x8), d=128, H=4, dk=32.
// Round 10: LDS B-operands restored with clean staging (pre-cast bf16 weights
// -> uint4 loads -> aligned b128 LDS writes; no f2bf scatter, no conflicts).
// k_prep folded into k_cond. k_attn unchanged from round 8/9.
// ws layout (bytes):
//   Qb  bf16 [64][4][512][32]   8 MB  (pre-scaled by log2e/sqrt(32))
//   Kb  bf16 [64][4][512][32]   8 MB
//   Vtb bf16 [64][4][32][512]   8 MB  (transposed [dk][n])
//   Ob  bf16 [64][512][128]     8 MB  (i-ordered: i = k*4+h, permute pre-applied)
//   mods f32 [64][6][128]      192 KB @ 33554432
//   cT  bf16 [3][128][128]      96 KB @ 33751040  (W^T per phase: [c][d])
//   owT bf16 [128][128]         32 KB @ 33849344  (owT[c][i] = ow[i][c])
// mods slots per b: 0=alpha1(g1), 1=gamma1(be1), 2=beta1(al1),
//                   3=alpha2(g2), 4=gamma2(be2), 5=beta2(al2)   (bug-faithful)

#define NB 64

typedef __attribute__((ext_vector_type(8))) short bf16x8;
typedef __attribute__((ext_vector_type(4))) float f32x4;

__device__ __forceinline__ float silu_f(float x) { return x / (1.0f + __expf(-x)); }
__device__ __forceinline__ unsigned short f2bf(float x) {
    __hip_bfloat16 h = __float2bfloat16(x);
    return *reinterpret_cast<unsigned short*>(&h);
}

// ---------------- K1: cond MLPs (blocks 0..255) + weight pre-cast (256..511) ----
__global__ void __launch_bounds__(128) k_cond(
    const float* __restrict__ nodes, const float* __restrict__ tv,
    const float* __restrict__ w10, const float* __restrict__ b10,
    const float* __restrict__ w20, const float* __restrict__ b20,
    const float* __restrict__ w30, const float* __restrict__ b30,
    const float* __restrict__ w11, const float* __restrict__ b11,
    const float* __restrict__ w21, const float* __restrict__ b21,
    const float* __restrict__ w31, const float* __restrict__ b31,
    const float* __restrict__ w12, const float* __restrict__ b12,
    const float* __restrict__ w22, const float* __restrict__ b22,
    const float* __restrict__ w32, const float* __restrict__ b32,
    const float* __restrict__ w13, const float* __restrict__ b13,
    const float* __restrict__ w23, const float* __restrict__ b23,
    const float* __restrict__ w33, const float* __restrict__ b33,
    float* __restrict__ mods,
    const float* __restrict__ qw, const float* __restrict__ kw,
    const float* __restrict__ vw, const float* __restrict__ ow,
    unsigned short* __restrict__ cT, unsigned short* __restrict__ owT)
{
    int blk = blockIdx.x;
    int t = threadIdx.x;

    if (blk >= NB*4) {
        // weight pre-cast: 65536 elements over 256 blocks x 128 threads x 2
        int pbase = (blk - NB*4)*128 + t;
        #pragma unroll
        for (int rep = 0; rep < 2; rep++) {
            int idx = pbase + rep*32768;
            if (idx < 49152) {
                int ph = idx >> 14, r = idx & 16383, c = r >> 7, d = r & 127;
                int h = c >> 5, kk = c & 31;
                const float* wp = ph==0 ? qw : (ph==1 ? kw : vw);
                cT[idx] = f2bf(wp[h*4096 + d*32 + kk]);
            } else {
                int r = idx - 49152, c = r >> 7, i = r & 127;
                owT[r] = f2bf(ow[i*128 + c]);
            }
        }
        return;
    }

    int b = blk >> 2, m = blk & 3;
    const float* W1 = m==0?w10 : m==1?w11 : m==2?w12 : w13;
    const float* B1 = m==0?b10 : m==1?b11 : m==2?b12 : b13;
    const float* W2 = m==0?w20 : m==1?w21 : m==2?w22 : w23;
    const float* B2 = m==0?b20 : m==1?b21 : m==2?b22 : b23;
    const float* W3 = m==0?w30 : m==1?w31 : m==2?w32 : w33;
    const float* B3 = m==0?b30 : m==1?b31 : m==2?b32 : b33;
    int dout256 = (m == 0 || m == 2);
    int slot = (m==0)?0 : (m==1)?2 : (m==2)?3 : 5;

    __shared__ float xs[128], h1[128], h2[128];
    xs[t] = nodes[b*128 + t] + tv[b];
    __syncthreads();

    float acc = B1[t];
    for (int i = 0; i < 128; i++) acc += xs[i] * W1[i*128 + t];
    h1[t] = silu_f(acc);
    __syncthreads();

    acc = B2[t];
    for (int i = 0; i < 128; i++) acc += h1[i] * W2[i*128 + t];
    h2[t] = silu_f(acc);
    __syncthreads();

    if (dout256) {
        float a0 = B3[t], a1 = B3[t + 128];
        for (int i = 0; i < 128; i++) {
            float h = h2[i];
            a0 += h * W3[i*256 + t];
            a1 += h * W3[i*256 + t + 128];
        }
        mods[((size_t)b*6 + slot    )*128 + t] = a0;
        mods[((size_t)b*6 + slot + 1)*128 + t] = a1;
    } else {
        float a0 = B3[t];
        for (int i = 0; i < 128; i++) a0 += h2[i] * W3[i*128 + t];
        mods[((size_t)b*6 + slot)*128 + t] = a0;
    }
}

// ---------------- K2: register-LN + modulate + MFMA QKV (LDS W, clean staging) ----
// grid = NB*8 blocks (b, 64-row tile), 256 threads (4 waves; wave = m-tile)
__global__ void __launch_bounds__(256, 3) k_norm_qkv(
    const float* __restrict__ latent, const float* __restrict__ mods,
    const unsigned short* __restrict__ cT,
    const float* __restrict__ qb, const float* __restrict__ kb, const float* __restrict__ vb,
    unsigned short* __restrict__ Qb, unsigned short* __restrict__ Kb,
    unsigned short* __restrict__ Vtb)
{
    __shared__ unsigned short xb[64*136];   // normalized bf16 [n][d]; reused as V staging [128][68]
    __shared__ unsigned short WtS[128*136]; // W^T bf16 [c][d], stride 136 (b128 reads 2-way ~ free)

    int blk = blockIdx.x;
    int b = blk >> 3, n0 = (blk & 7) * 64;
    int t = threadIdx.x;
    int j = t >> 2, sub = t & 3;            // row j (0..63), d-quarter sub

    // --- load 32 raw f32 for (row n0+j, d = sub*32 + i) ---
    const float* lp = latent + (size_t)b*65536 + n0 + j;
    float lat[32];
    #pragma unroll
    for (int i = 0; i < 32; i++)
        lat[i] = lp[(size_t)(sub*32 + i)*512];

    // --- LN stats (ddof=1) via 2 shfl over the 4 subs of this row ---
    float s = 0.f, ss = 0.f;
    #pragma unroll
    for (int i = 0; i < 32; i++) { s += lat[i]; ss += lat[i]*lat[i]; }
    s += __shfl_xor(s, 1); ss += __shfl_xor(ss, 1);
    s += __shfl_xor(s, 2); ss += __shfl_xor(ss, 2);
    float mean = s * (1.0f/128.0f);
    float var = (ss - 128.0f*mean*mean) * (1.0f/127.0f);
    var = var < 0.f ? 0.f : var;
    float sd = sqrtf(var);
    float rstd = (sd == 0.f) ? 1.f : 1.f/sd;

    // --- modulate (gamma1=be1, beta1=al1 : bug-faithful), pack bf16 pairs ---
    const float* g1p  = mods + ((size_t)b*6 + 1)*128 + sub*32;
    const float* be1p = mods + ((size_t)b*6 + 2)*128 + sub*32;
    unsigned int* xbw = (unsigned int*)xb + j*68 + sub*16;
    #pragma unroll
    for (int i2 = 0; i2 < 16; i2++) {
        float v0 = g1p[2*i2]   * ((lat[2*i2]   - mean)*rstd) + be1p[2*i2];
        float v1 = g1p[2*i2+1] * ((lat[2*i2+1] - mean)*rstd) + be1p[2*i2+1];
        xbw[i2] = (unsigned)f2bf(v0) | ((unsigned)f2bf(v1) << 16);
    }
    __syncthreads();

    int w = t >> 6, lane = t & 63, lo = lane & 15, hi = lane >> 4;
    bf16x8 af[4];
    #pragma unroll
    for (int kc = 0; kc < 4; kc++)
        af[kc] = *(const bf16x8*)(xb + (w*16 + lo)*136 + kc*32 + hi*8);

    const f32x4 zero = {0.f, 0.f, 0.f, 0.f};
    const float qscale = 0.17677669529663687f * 1.4426950408889634f; // 1/sqrt(32)*log2e
    unsigned int* WtSw = (unsigned int*)WtS;

    #pragma unroll 1
    for (int ph = 0; ph < 3; ph++) {
        __syncthreads();   // prior phase's WtS reads (and ph0: af reads) complete
        // stage W^T: 2048 uint4 from cT -> b128 LDS writes at stride-136 rows
        {
            const uint4* cq = (const uint4*)(cT + ph*16384);
            #pragma unroll
            for (int k = 0; k < 8; k++) {
                int idx4 = t + k*256;                 // 0..2047
                int c = idx4 >> 4, d2b = (idx4 & 15)*4;
                uint4 v = cq[idx4];
                *(uint4*)(WtSw + c*68 + d2b) = v;
            }
        }
        __syncthreads();

        for (int nt = 0; nt < 8; nt++) {
            f32x4 acc = zero;
            #pragma unroll
            for (int kc = 0; kc < 4; kc++) {
                bf16x8 bf = *(const bf16x8*)(WtS + (nt*16 + lo)*136 + kc*32 + hi*8);
                acc = __builtin_amdgcn_mfma_f32_16x16x32_bf16(af[kc], bf, acc, 0, 0, 0);
            }
            int c = nt*16 + lo, h = c >> 5, kk = c & 31;
            size_t bh = (size_t)(b*4 + h);
            if (ph == 0) {
                float bias = qb[c];
                #pragma unroll
                for (int jj = 0; jj < 4; jj++) {
                    int n = n0 + w*16 + hi*4 + jj;
                    Qb[(bh*512 + n)*32 + kk] = f2bf((acc[jj] + bias) * qscale);
                }
            } else if (ph == 1) {
                float bias = kb[c];
                #pragma unroll
                for (int jj = 0; jj < 4; jj++) {
                    int n = n0 + w*16 + hi*4 + jj;
                    Kb[(bh*512 + n)*32 + kk] = f2bf(acc[jj] + bias);
                }
            } else {
                float bias = vb[c];
                #pragma unroll
                for (int jj = 0; jj < 4; jj++) {
                    int nl = w*16 + hi*4 + jj;
                    xb[c*68 + nl] = f2bf(acc[jj] + bias);
                }
            }
        }
    }
    __syncthreads();
    // V write-out: Vtb[bh][kk][n0..n0+63], coalesced 64-wide
    for (int idx = t; idx < 8192; idx += 256) {
        int c = idx >> 6, jj = idx & 63;
        int h = c >> 5, kk = c & 31;
        size_t bh = (size_t)(b*4 + h);
        Vtb[(bh*32 + kk)*512 + n0 + jj] = xb[c*68 + jj];
    }
}

// ---------------- K3: MFMA attention, online-softmax chunked (unchanged) ----
// grid = NB*4*2 blocks (bh, q-half), 512 threads (8 waves).
__global__ void __launch_bounds__(512, 4) k_attn(
    const unsigned short* __restrict__ Qb, const unsigned short* __restrict__ Kb,
    const unsigned short* __restrict__ Vtb, unsigned short* __restrict__ Ob)
{
    __shared__ unsigned short KsS[512*32];   // [key][dk] linear
    __shared__ unsigned short VsS[32*512];   // [dk][key], col ^= (row&7)<<3

    int blk = blockIdx.x;
    int bh = blk >> 1, qhalf = blk & 1;
    int t = threadIdx.x;

    const unsigned short* kgp = Kb + (size_t)bh*512*32;
    const unsigned short* vgp = Vtb + (size_t)bh*32*512;
    for (int idx = t; idx < 2048; idx += 512)
        *(bf16x8*)(KsS + idx*8) = *(const bf16x8*)(kgp + idx*8);
    for (int idx = t; idx < 2048; idx += 512) {
        int r = idx >> 6, cch = idx & 63;
        *(bf16x8*)(VsS + r*512 + ((cch*8) ^ ((r&7)<<3))) =
            *(const bf16x8*)(vgp + r*512 + cch*8);
    }
    __syncthreads();

    int w = t >> 6, lane = t & 63, lo = lane & 15, hi = lane >> 4;
    const unsigned short* qbase = Qb + (size_t)bh*512*32;
    const f32x4 zero = {0.f, 0.f, 0.f, 0.f};
    int b = bh >> 2, h = bh & 3;

    const unsigned short* Vl0 = VsS + lo*512;
    const unsigned short* Vl1 = VsS + (16 + lo)*512;
    int swz = (lo & 7) << 3;
    int srcA = lo + 32*(hi & 1);

    for (int qt = 0; qt < 2; ++qt) {
        int q0 = qhalf*256 + w*32 + qt*16;
        bf16x8 qa = *(const bf16x8*)(qbase + (size_t)(q0 + lo)*32 + hi*8);

        float m = -1e30f, sum = 0.f;
        f32x4 oa = zero, ob = zero;

        #pragma unroll 1
        for (int ch = 0; ch < 4; ++ch) {
            f32x4 s8[8];
            #pragma unroll
            for (int kt = 0; kt < 8; ++kt) {
                bf16x8 kf = *(const bf16x8*)(KsS + ((ch*8 + kt)*16 + lo)*32 + hi*8);
                s8[kt] = __builtin_amdgcn_mfma_f32_16x16x32_bf16(kf, qa, zero, 0, 0, 0);
            }

            float cm = -1e30f;
            #pragma unroll
            for (int kt = 0; kt < 8; ++kt)
                cm = fmaxf(cm, fmaxf(fmaxf(s8[kt][0], s8[kt][1]), fmaxf(s8[kt][2], s8[kt][3])));
            cm = fmaxf(cm, __shfl_xor(cm, 16));
            cm = fmaxf(cm, __shfl_xor(cm, 32));
            float nm = fmaxf(m, cm);
            float sc = __builtin_amdgcn_exp2f(m - nm);
            sum *= sc;
            #pragma unroll
            for (int jj = 0; jj < 4; ++jj) { oa[jj] *= sc; ob[jj] *= sc; }
            m = nm;

            unsigned pw0c[8], pw1c[8];
            #pragma unroll
            for (int kt = 0; kt < 8; ++kt) {
                float p0 = __builtin_amdgcn_exp2f(s8[kt][0] - nm);
                float p1 = __builtin_amdgcn_exp2f(s8[kt][1] - nm);
                float p2 = __builtin_amdgcn_exp2f(s8[kt][2] - nm);
                float p3 = __builtin_amdgcn_exp2f(s8[kt][3] - nm);
                sum += (p0 + p1) + (p2 + p3);
                pw0c[kt] = (unsigned)f2bf(p0) | ((unsigned)f2bf(p1) << 16);
                pw1c[kt] = (unsigned)f2bf(p2) | ((unsigned)f2bf(p3) << 16);
            }

            #pragma unroll
            for (int kt2 = 0; kt2 < 4; ++kt2) {
                unsigned e0 = pw0c[2*kt2],     e1 = pw1c[2*kt2];
                unsigned o0 = pw0c[2*kt2 + 1], o1 = pw1c[2*kt2 + 1];
                unsigned ae0 = (unsigned)__shfl((int)e0, srcA, 64);
                unsigned ae1 = (unsigned)__shfl((int)e1, srcA, 64);
                unsigned ao0 = (unsigned)__shfl((int)o0, srcA, 64);
                unsigned ao1 = (unsigned)__shfl((int)o1, srcA, 64);
                unsigned be0 = (unsigned)__shfl((int)e0, srcA + 16, 64);
                unsigned be1 = (unsigned)__shfl((int)e1, srcA + 16, 64);
                unsigned bo0 = (unsigned)__shfl((int)o0, srcA + 16, 64);
                unsigned bo1 = (unsigned)__shfl((int)o1, srcA + 16, 64);
                union { unsigned u[4]; bf16x8 v; } pb;
                pb.u[0] = (hi < 2) ? ae0 : ao0;
                pb.u[1] = (hi < 2) ? ae1 : ao1;
                pb.u[2] = (hi < 2) ? be0 : bo0;
                pb.u[3] = (hi < 2) ? be1 : bo1;
                int off = (((ch*4 + kt2)*32) + hi*8) ^ swz;
                bf16x8 v0 = *(const bf16x8*)(Vl0 + off);
                bf16x8 v1 = *(const bf16x8*)(Vl1 + off);
                oa = __builtin_amdgcn_mfma_f32_16x16x32_bf16(v0, pb.v, oa, 0, 0, 0);
                ob = __builtin_amdgcn_mfma_f32_16x16x32_bf16(v1, pb.v, ob, 0, 0, 0);
            }
        }

        sum += __shfl_xor(sum, 16);
        sum += __shfl_xor(sum, 32);

        float inv = 1.f / sum;
        unsigned short* op = Ob + ((size_t)(b*512 + q0 + lo))*128 + h;
        #pragma unroll
        for (int jj = 0; jj < 4; ++jj) {
            op[(hi*4 + jj)*4]       = f2bf(oa[jj] * inv);
            op[(16 + hi*4 + jj)*4]  = f2bf(ob[jj] * inv);
        }
    }
}

// ---------------- K4: MFMA O@ow (LDS owT, clean staging) + residual + LN2 ----
// grid = NB*8 blocks, 256 threads (4 waves; wave = m-tile)
__global__ void __launch_bounds__(256, 2) k_out(
    const float* __restrict__ latent, const unsigned short* __restrict__ Ob,
    const unsigned short* __restrict__ owT, const float* __restrict__ mods,
    float* __restrict__ outp)
{
    __shared__ unsigned short owS[128*136];  // ow^T bf16 [c][i], stride 136
    __shared__ float xs[64*129];
    __shared__ float a1s[128], a2s[128], g2s[128], b2s[128];
    __shared__ float mean_s[64], rstd_s[64];

    int blk = blockIdx.x;
    int b = blk >> 3, n0 = (blk & 7) * 64;
    int t = threadIdx.x;

    if (t < 128) {
        a1s[t] = mods[((size_t)b*6 + 0)*128 + t];  // alpha1 = g1 (bug)
        a2s[t] = mods[((size_t)b*6 + 3)*128 + t];  // alpha2 = g2 (bug)
        g2s[t] = mods[((size_t)b*6 + 4)*128 + t];  // gamma2 = be2 (bug)
        b2s[t] = mods[((size_t)b*6 + 5)*128 + t];  // beta2  = al2 (bug)
    }
    {
        unsigned int* owSw = (unsigned int*)owS;
        const uint4* oq = (const uint4*)owT;
        #pragma unroll
        for (int k = 0; k < 8; k++) {
            int idx4 = t + k*256;                 // 0..2047
            int c = idx4 >> 4, d2b = (idx4 & 15)*4;
            uint4 v = oq[idx4];
            *(uint4*)(owSw + c*68 + d2b) = v;
        }
    }
    const float* lp = latent + (size_t)b*65536 + n0;
    for (int idx = t; idx < 8192; idx += 256) {
        int d = idx >> 6, jj = idx & 63;
        xs[jj*129 + d] = lp[(size_t)d*512 + jj];
    }
    __syncthreads();

    int w = t >> 6, lane = t & 63, lo = lane & 15, hi = lane >> 4;

    const unsigned short* arow = Ob + ((size_t)(b*512 + n0 + w*16 + lo))*128;
    bf16x8 af[4];
    #pragma unroll
    for (int kc = 0; kc < 4; kc++)
        af[kc] = *(const bf16x8*)(arow + kc*32 + hi*8);

    const f32x4 zero = {0.f, 0.f, 0.f, 0.f};
    for (int nt = 0; nt < 8; nt++) {
        f32x4 acc = zero;
        #pragma unroll
        for (int kc = 0; kc < 4; kc++) {
            bf16x8 bf = *(const bf16x8*)(owS + (nt*16 + lo)*136 + kc*32 + hi*8);
            acc = __builtin_amdgcn_mfma_f32_16x16x32_bf16(af[kc], bf, acc, 0, 0, 0);
        }
        int c = nt*16 + lo;
        #pragma unroll
        for (int jj = 0; jj < 4; jj++) {
            int nl = w*16 + hi*4 + jj;
            xs[nl*129 + c] += a1s[c] * acc[jj];
        }
    }
    __syncthreads();

    {
        int row = t >> 2, sub = t & 3;
        float s = 0.f, ss = 0.f;
        const float* xr = &xs[row*129 + sub*32];
        #pragma unroll
        for (int i = 0; i < 32; i++) { float v = xr[i]; s += v; ss += v*v; }
        s += __shfl_xor(s, 1); ss += __shfl_xor(ss, 1);
        s += __shfl_xor(s, 2); ss += __shfl_xor(ss, 2);
        float mean = s * (1.0f/128.0f);
        float var = (ss - 128.0f*mean*mean) * (1.0f/127.0f);
        var = var < 0.f ? 0.f : var;
        float sd = sqrtf(var);
        mean_s[row] = mean;
        rstd_s[row] = (sd == 0.f) ? 1.f : 1.f/sd;
    }
    __syncthreads();

    float* outb = outp + (size_t)b*65536 + n0;
    for (int idx = t; idx < 8192; idx += 256) {
        int d = idx >> 6, jj = idx & 63;
        float v = xs[jj*129 + d];
        float nv = (v - mean_s[jj]) * rstd_s[jj];
        outb[(size_t)d*512 + jj] = v + a2s[d]*(g2s[d]*nv + b2s[d]);
    }
}

extern "C" void kernel_launch(void* const* d_in, const int* in_sizes, int n_in,
                              void* d_out, int out_size, void* d_ws, size_t ws_size,
                              hipStream_t stream) {
    const float* latent = (const float*)d_in[0];
    const float* nodes  = (const float*)d_in[1];
    const float* tv     = (const float*)d_in[2];
    const float* qw     = (const float*)d_in[3];
    const float* kw     = (const float*)d_in[4];
    const float* vw     = (const float*)d_in[5];
    const float* qb     = (const float*)d_in[6];
    const float* kb     = (const float*)d_in[7];
    const float* vb     = (const float*)d_in[8];
    const float* owp    = (const float*)d_in[9];

    const float* mw[24];
    for (int i = 0; i < 24; i++) mw[i] = (const float*)d_in[10 + i];

    char* wsb = (char*)d_ws;
    unsigned short* Qb  = (unsigned short*)(wsb);
    unsigned short* Kb  = (unsigned short*)(wsb + 8388608);
    unsigned short* Vtb = (unsigned short*)(wsb + 16777216);
    unsigned short* Ob  = (unsigned short*)(wsb + 25165824);
    float* mods         = (float*)(wsb + 33554432);
    unsigned short* cT  = (unsigned short*)(wsb + 33751040);
    unsigned short* owT = (unsigned short*)(wsb + 33849344);

    float* outp = (float*)d_out;

    k_cond<<<dim3(NB*4 + 256), dim3(128), 0, stream>>>(
        nodes, tv,
        mw[0], mw[1], mw[2], mw[3], mw[4], mw[5],
        mw[6], mw[7], mw[8], mw[9], mw[10], mw[11],
        mw[12], mw[13], mw[14], mw[15], mw[16], mw[17],
        mw[18], mw[19], mw[20], mw[21], mw[22], mw[23],
        mods,
        qw, kw, vw, owp, cT, owT);

    k_norm_qkv<<<dim3(NB*8), dim3(256), 0, stream>>>(
        latent, mods, cT, qb, kb, vb, Qb, Kb, Vtb);

    k_attn<<<dim3(NB*4*2), dim3(512), 0, stream>>>(Qb, Kb, Vtb, Ob);

    k_out<<<dim3(NB*8), dim3(256), 0, stream>>>(latent, Ob, owT, mods, outp);
}

// Round 11
// 198.886 us; speedup vs baseline: 1.1375x; 1.0098x over previous
//
#include <hip/hip_runtime.h>
#include <hip/hip_bf16.h>
#include <math.h>

// DiT block. b=64, n=512 (8x8x8), d=128, H=4, dk=32.
// Round 11: Ob stored in sc-order (h*32+dk) with packed dwordx2 stores
// (i-permute folded into owT pre-cast); k_out float4 VMEM; k_attn defer-max.
// ws layout (bytes):
//   Qb  bf16 [64][4][512][32]   8 MB  (pre-scaled by log2e/sqrt(32))
//   Kb  bf16 [64][4][512][32]   8 MB
//   Vtb bf16 [64][4][32][512]   8 MB  (transposed [dk][n])
//   Ob  bf16 [64][512][128]     8 MB  (sc-order: col = h*32+dk)
//   mods f32 [64][6][128]      192 KB @ 33554432
//   cT  bf16 [3][128][128]      96 KB @ 33751040  (W^T per phase: [c][d])
//   owT bf16 [128][128]         32 KB @ 33849344  (owT[c][sc] = ow[i(sc)][c])
// mods slots per b: 0=alpha1(g1), 1=gamma1(be1), 2=beta1(al1),
//                   3=alpha2(g2), 4=gamma2(be2), 5=beta2(al2)   (bug-faithful)

#define NB 64

typedef __attribute__((ext_vector_type(8))) short bf16x8;
typedef __attribute__((ext_vector_type(4))) float f32x4;

__device__ __forceinline__ float silu_f(float x) { return x / (1.0f + __expf(-x)); }
__device__ __forceinline__ unsigned short f2bf(float x) {
    __hip_bfloat16 h = __float2bfloat16(x);
    return *reinterpret_cast<unsigned short*>(&h);
}

// ---------------- K1: cond MLPs (blocks 0..255) + weight pre-cast (256..511) ----
__global__ void __launch_bounds__(128) k_cond(
    const float* __restrict__ nodes, const float* __restrict__ tv,
    const float* __restrict__ w10, const float* __restrict__ b10,
    const float* __restrict__ w20, const float* __restrict__ b20,
    const float* __restrict__ w30, const float* __restrict__ b30,
    const float* __restrict__ w11, const float* __restrict__ b11,
    const float* __restrict__ w21, const float* __restrict__ b21,
    const float* __restrict__ w31, const float* __restrict__ b31,
    const float* __restrict__ w12, const float* __restrict__ b12,
    const float* __restrict__ w22, const float* __restrict__ b22,
    const float* __restrict__ w32, const float* __restrict__ b32,
    const float* __restrict__ w13, const float* __restrict__ b13,
    const float* __restrict__ w23, const float* __restrict__ b23,
    const float* __restrict__ w33, const float* __restrict__ b33,
    float* __restrict__ mods,
    const float* __restrict__ qw, const float* __restrict__ kw,
    const float* __restrict__ vw, const float* __restrict__ ow,
    unsigned short* __restrict__ cT, unsigned short* __restrict__ owT)
{
    int blk = blockIdx.x;
    int t = threadIdx.x;

    if (blk >= NB*4) {
        // weight pre-cast: 65536 elements over 256 blocks x 128 threads x 2
        int pbase = (blk - NB*4)*128 + t;
        #pragma unroll
        for (int rep = 0; rep < 2; rep++) {
            int idx = pbase + rep*32768;
            if (idx < 49152) {
                int ph = idx >> 14, r = idx & 16383, c = r >> 7, d = r & 127;
                int h = c >> 5, kk = c & 31;
                const float* wp = ph==0 ? qw : (ph==1 ? kw : vw);
                cT[idx] = f2bf(wp[h*4096 + d*32 + kk]);
            } else {
                // owT[c][sc] = ow[i(sc)][c], i(sc) = (sc&31)*4 + (sc>>5)
                int r = idx - 49152, c = r >> 7, sc = r & 127;
                int i = (sc & 31)*4 + (sc >> 5);
                owT[r] = f2bf(ow[i*128 + c]);
            }
        }
        return;
    }

    int b = blk >> 2, m = blk & 3;
    const float* W1 = m==0?w10 : m==1?w11 : m==2?w12 : w13;
    const float* B1 = m==0?b10 : m==1?b11 : m==2?b12 : b13;
    const float* W2 = m==0?w20 : m==1?w21 : m==2?w22 : w23;
    const float* B2 = m==0?b20 : m==1?b21 : m==2?b22 : b23;
    const float* W3 = m==0?w30 : m==1?w31 : m==2?w32 : w33;
    const float* B3 = m==0?b30 : m==1?b31 : m==2?b32 : b33;
    int dout256 = (m == 0 || m == 2);
    int slot = (m==0)?0 : (m==1)?2 : (m==2)?3 : 5;

    __shared__ float xs[128], h1[128], h2[128];
    xs[t] = nodes[b*128 + t] + tv[b];
    __syncthreads();

    float acc = B1[t];
    for (int i = 0; i < 128; i++) acc += xs[i] * W1[i*128 + t];
    h1[t] = silu_f(acc);
    __syncthreads();

    acc = B2[t];
    for (int i = 0; i < 128; i++) acc += h1[i] * W2[i*128 + t];
    h2[t] = silu_f(acc);
    __syncthreads();

    if (dout256) {
        float a0 = B3[t], a1 = B3[t + 128];
        for (int i = 0; i < 128; i++) {
            float h = h2[i];
            a0 += h * W3[i*256 + t];
            a1 += h * W3[i*256 + t + 128];
        }
        mods[((size_t)b*6 + slot    )*128 + t] = a0;
        mods[((size_t)b*6 + slot + 1)*128 + t] = a1;
    } else {
        float a0 = B3[t];
        for (int i = 0; i < 128; i++) a0 += h2[i] * W3[i*128 + t];
        mods[((size_t)b*6 + slot)*128 + t] = a0;
    }
}

// ---------------- K2: register-LN + modulate + MFMA QKV (LDS W, clean staging) ----
// grid = NB*8 blocks (b, 64-row tile), 256 threads (4 waves; wave = m-tile)
__global__ void __launch_bounds__(256, 3) k_norm_qkv(
    const float* __restrict__ latent, const float* __restrict__ mods,
    const unsigned short* __restrict__ cT,
    const float* __restrict__ qb, const float* __restrict__ kb, const float* __restrict__ vb,
    unsigned short* __restrict__ Qb, unsigned short* __restrict__ Kb,
    unsigned short* __restrict__ Vtb)
{
    __shared__ unsigned short xb[64*136];   // normalized bf16 [n][d]; reused as V staging [128][68]
    __shared__ unsigned short WtS[128*136]; // W^T bf16 [c][d], stride 136

    int blk = blockIdx.x;
    int b = blk >> 3, n0 = (blk & 7) * 64;
    int t = threadIdx.x;
    int j = t >> 2, sub = t & 3;            // row j (0..63), d-quarter sub

    const float* lp = latent + (size_t)b*65536 + n0 + j;
    float lat[32];
    #pragma unroll
    for (int i = 0; i < 32; i++)
        lat[i] = lp[(size_t)(sub*32 + i)*512];

    float s = 0.f, ss = 0.f;
    #pragma unroll
    for (int i = 0; i < 32; i++) { s += lat[i]; ss += lat[i]*lat[i]; }
    s += __shfl_xor(s, 1); ss += __shfl_xor(ss, 1);
    s += __shfl_xor(s, 2); ss += __shfl_xor(ss, 2);
    float mean = s * (1.0f/128.0f);
    float var = (ss - 128.0f*mean*mean) * (1.0f/127.0f);
    var = var < 0.f ? 0.f : var;
    float sd = sqrtf(var);
    float rstd = (sd == 0.f) ? 1.f : 1.f/sd;

    const float* g1p  = mods + ((size_t)b*6 + 1)*128 + sub*32;  // gamma1 = be1 (bug)
    const float* be1p = mods + ((size_t)b*6 + 2)*128 + sub*32;  // beta1  = al1 (bug)
    unsigned int* xbw = (unsigned int*)xb + j*68 + sub*16;
    #pragma unroll
    for (int i2 = 0; i2 < 16; i2++) {
        float v0 = g1p[2*i2]   * ((lat[2*i2]   - mean)*rstd) + be1p[2*i2];
        float v1 = g1p[2*i2+1] * ((lat[2*i2+1] - mean)*rstd) + be1p[2*i2+1];
        xbw[i2] = (unsigned)f2bf(v0) | ((unsigned)f2bf(v1) << 16);
    }
    __syncthreads();

    int w = t >> 6, lane = t & 63, lo = lane & 15, hi = lane >> 4;
    bf16x8 af[4];
    #pragma unroll
    for (int kc = 0; kc < 4; kc++)
        af[kc] = *(const bf16x8*)(xb + (w*16 + lo)*136 + kc*32 + hi*8);

    const f32x4 zero = {0.f, 0.f, 0.f, 0.f};
    const float qscale = 0.17677669529663687f * 1.4426950408889634f; // 1/sqrt(32)*log2e
    unsigned int* WtSw = (unsigned int*)WtS;

    #pragma unroll 1
    for (int ph = 0; ph < 3; ph++) {
        __syncthreads();
        {
            const uint4* cq = (const uint4*)(cT + ph*16384);
            #pragma unroll
            for (int k = 0; k < 8; k++) {
                int idx4 = t + k*256;
                int c = idx4 >> 4, d2b = (idx4 & 15)*4;
                uint4 v = cq[idx4];
                *(uint4*)(WtSw + c*68 + d2b) = v;
            }
        }
        __syncthreads();

        for (int nt = 0; nt < 8; nt++) {
            f32x4 acc = zero;
            #pragma unroll
            for (int kc = 0; kc < 4; kc++) {
                bf16x8 bf = *(const bf16x8*)(WtS + (nt*16 + lo)*136 + kc*32 + hi*8);
                acc = __builtin_amdgcn_mfma_f32_16x16x32_bf16(af[kc], bf, acc, 0, 0, 0);
            }
            int c = nt*16 + lo, h = c >> 5, kk = c & 31;
            size_t bh = (size_t)(b*4 + h);
            if (ph == 0) {
                float bias = qb[c];
                #pragma unroll
                for (int jj = 0; jj < 4; jj++) {
                    int n = n0 + w*16 + hi*4 + jj;
                    Qb[(bh*512 + n)*32 + kk] = f2bf((acc[jj] + bias) * qscale);
                }
            } else if (ph == 1) {
                float bias = kb[c];
                #pragma unroll
                for (int jj = 0; jj < 4; jj++) {
                    int n = n0 + w*16 + hi*4 + jj;
                    Kb[(bh*512 + n)*32 + kk] = f2bf(acc[jj] + bias);
                }
            } else {
                float bias = vb[c];
                #pragma unroll
                for (int jj = 0; jj < 4; jj++) {
                    int nl = w*16 + hi*4 + jj;
                    xb[c*68 + nl] = f2bf(acc[jj] + bias);
                }
            }
        }
    }
    __syncthreads();
    for (int idx = t; idx < 8192; idx += 256) {
        int c = idx >> 6, jj = idx & 63;
        int h = c >> 5, kk = c & 31;
        size_t bh = (size_t)(b*4 + h);
        Vtb[(bh*32 + kk)*512 + n0 + jj] = xb[c*68 + jj];
    }
}

// ---------------- K3: MFMA attention, online-softmax chunked + defer-max ----
// grid = NB*4*2 blocks (bh, q-half), 512 threads (8 waves).
__global__ void __launch_bounds__(512, 4) k_attn(
    const unsigned short* __restrict__ Qb, const unsigned short* __restrict__ Kb,
    const unsigned short* __restrict__ Vtb, unsigned short* __restrict__ Ob)
{
    __shared__ unsigned short KsS[512*32];   // [key][dk] linear
    __shared__ unsigned short VsS[32*512];   // [dk][key], col ^= (row&7)<<3

    int blk = blockIdx.x;
    int bh = blk >> 1, qhalf = blk & 1;
    int t = threadIdx.x;

    const unsigned short* kgp = Kb + (size_t)bh*512*32;
    const unsigned short* vgp = Vtb + (size_t)bh*32*512;
    for (int idx = t; idx < 2048; idx += 512)
        *(bf16x8*)(KsS + idx*8) = *(const bf16x8*)(kgp + idx*8);
    for (int idx = t; idx < 2048; idx += 512) {
        int r = idx >> 6, cch = idx & 63;
        *(bf16x8*)(VsS + r*512 + ((cch*8) ^ ((r&7)<<3))) =
            *(const bf16x8*)(vgp + r*512 + cch*8);
    }
    __syncthreads();

    int w = t >> 6, lane = t & 63, lo = lane & 15, hi = lane >> 4;
    const unsigned short* qbase = Qb + (size_t)bh*512*32;
    const f32x4 zero = {0.f, 0.f, 0.f, 0.f};
    int b = bh >> 2, h = bh & 3;

    const unsigned short* Vl0 = VsS + lo*512;
    const unsigned short* Vl1 = VsS + (16 + lo)*512;
    int swz = (lo & 7) << 3;
    int srcA = lo + 32*(hi & 1);

    for (int qt = 0; qt < 2; ++qt) {
        int q0 = qhalf*256 + w*32 + qt*16;
        bf16x8 qa = *(const bf16x8*)(qbase + (size_t)(q0 + lo)*32 + hi*8);

        float m = -1e30f, sum = 0.f;
        f32x4 oa = zero, ob = zero;

        #pragma unroll 1
        for (int ch = 0; ch < 4; ++ch) {
            f32x4 s8[8];
            #pragma unroll
            for (int kt = 0; kt < 8; ++kt) {
                bf16x8 kf = *(const bf16x8*)(KsS + ((ch*8 + kt)*16 + lo)*32 + hi*8);
                s8[kt] = __builtin_amdgcn_mfma_f32_16x16x32_bf16(kf, qa, zero, 0, 0, 0);
            }

            float cm = -1e30f;
            #pragma unroll
            for (int kt = 0; kt < 8; ++kt)
                cm = fmaxf(cm, fmaxf(fmaxf(s8[kt][0], s8[kt][1]), fmaxf(s8[kt][2], s8[kt][3])));
            cm = fmaxf(cm, __shfl_xor(cm, 16));
            cm = fmaxf(cm, __shfl_xor(cm, 32));
            // defer-max (T13): only rescale when some row grew by > 8 (P <= 2^8, safe)
            if (!__all(cm - m <= 8.0f)) {
                float nm = fmaxf(m, cm);
                float sc = __builtin_amdgcn_exp2f(m - nm);
                sum *= sc;
                #pragma unroll
                for (int jj = 0; jj < 4; ++jj) { oa[jj] *= sc; ob[jj] *= sc; }
                m = nm;
            }

            unsigned pw0c[8], pw1c[8];
            #pragma unroll
            for (int kt = 0; kt < 8; ++kt) {
                float p0 = __builtin_amdgcn_exp2f(s8[kt][0] - m);
                float p1 = __builtin_amdgcn_exp2f(s8[kt][1] - m);
                float p2 = __builtin_amdgcn_exp2f(s8[kt][2] - m);
                float p3 = __builtin_amdgcn_exp2f(s8[kt][3] - m);
                sum += (p0 + p1) + (p2 + p3);
                pw0c[kt] = (unsigned)f2bf(p0) | ((unsigned)f2bf(p1) << 16);
                pw1c[kt] = (unsigned)f2bf(p2) | ((unsigned)f2bf(p3) << 16);
            }

            #pragma unroll
            for (int kt2 = 0; kt2 < 4; ++kt2) {
                unsigned e0 = pw0c[2*kt2],     e1 = pw1c[2*kt2];
                unsigned o0 = pw0c[2*kt2 + 1], o1 = pw1c[2*kt2 + 1];
                unsigned ae0 = (unsigned)__shfl((int)e0, srcA, 64);
                unsigned ae1 = (unsigned)__shfl((int)e1, srcA, 64);
                unsigned ao0 = (unsigned)__shfl((int)o0, srcA, 64);
                unsigned ao1 = (unsigned)__shfl((int)o1, srcA, 64);
                unsigned be0 = (unsigned)__shfl((int)e0, srcA + 16, 64);
                unsigned be1 = (unsigned)__shfl((int)e1, srcA + 16, 64);
                unsigned bo0 = (unsigned)__shfl((int)o0, srcA + 16, 64);
                unsigned bo1 = (unsigned)__shfl((int)o1, srcA + 16, 64);
                union { unsigned u[4]; bf16x8 v; } pb;
                pb.u[0] = (hi < 2) ? ae0 : ao0;
                pb.u[1] = (hi < 2) ? ae1 : ao1;
                pb.u[2] = (hi < 2) ? be0 : bo0;
                pb.u[3] = (hi < 2) ? be1 : bo1;
                int off = (((ch*4 + kt2)*32) + hi*8) ^ swz;
                bf16x8 v0 = *(const bf16x8*)(Vl0 + off);
                bf16x8 v1 = *(const bf16x8*)(Vl1 + off);
                oa = __builtin_amdgcn_mfma_f32_16x16x32_bf16(v0, pb.v, oa, 0, 0, 0);
                ob = __builtin_amdgcn_mfma_f32_16x16x32_bf16(v1, pb.v, ob, 0, 0, 0);
            }
        }

        sum += __shfl_xor(sum, 16);
        sum += __shfl_xor(sum, 32);

        // --- store sc-order: Ob[n][h*32 + d], d = hi*4+j (+16); packed dwordx2 ---
        float inv = 1.f / sum;
        unsigned int* opw = (unsigned int*)(Ob + ((size_t)(b*512 + q0 + lo))*128 + h*32);
        uint2 ua, ub;
        ua.x = (unsigned)f2bf(oa[0]*inv) | ((unsigned)f2bf(oa[1]*inv) << 16);
        ua.y = (unsigned)f2bf(oa[2]*inv) | ((unsigned)f2bf(oa[3]*inv) << 16);
        ub.x = (unsigned)f2bf(ob[0]*inv) | ((unsigned)f2bf(ob[1]*inv) << 16);
        ub.y = (unsigned)f2bf(ob[2]*inv) | ((unsigned)f2bf(ob[3]*inv) << 16);
        *(uint2*)(opw + hi*2)     = ua;
        *(uint2*)(opw + 8 + hi*2) = ub;
    }
}

// ---------------- K4: MFMA O@ow (LDS owT) + residual + LN2 + residual ----
// grid = NB*8 blocks, 256 threads (4 waves; wave = m-tile)
__global__ void __launch_bounds__(256, 2) k_out(
    const float* __restrict__ latent, const unsigned short* __restrict__ Ob,
    const unsigned short* __restrict__ owT, const float* __restrict__ mods,
    float* __restrict__ outp)
{
    __shared__ unsigned short owS[128*136];  // owT staged [c][sc], stride 136
    __shared__ float xs[64*129];
    __shared__ float a1s[128], a2s[128], g2s[128], b2s[128];
    __shared__ float mean_s[64], rstd_s[64];

    int blk = blockIdx.x;
    int b = blk >> 3, n0 = (blk & 7) * 64;
    int t = threadIdx.x;

    if (t < 128) {
        a1s[t] = mods[((size_t)b*6 + 0)*128 + t];  // alpha1 = g1 (bug)
        a2s[t] = mods[((size_t)b*6 + 3)*128 + t];  // alpha2 = g2 (bug)
        g2s[t] = mods[((size_t)b*6 + 4)*128 + t];  // gamma2 = be2 (bug)
        b2s[t] = mods[((size_t)b*6 + 5)*128 + t];  // beta2  = al2 (bug)
    }
    {
        unsigned int* owSw = (unsigned int*)owS;
        const uint4* oq = (const uint4*)owT;
        #pragma unroll
        for (int k = 0; k < 8; k++) {
            int idx4 = t + k*256;
            int c = idx4 >> 4, d2b = (idx4 & 15)*4;
            uint4 v = oq[idx4];
            *(uint4*)(owSw + c*68 + d2b) = v;
        }
    }
    const float* lp = latent + (size_t)b*65536 + n0;
    for (int idx = t; idx < 2048; idx += 256) {
        int d = idx >> 4, j4 = (idx & 15)*4;
        float4 v = *(const float4*)(lp + (size_t)d*512 + j4);
        xs[(j4+0)*129 + d] = v.x;
        xs[(j4+1)*129 + d] = v.y;
        xs[(j4+2)*129 + d] = v.z;
        xs[(j4+3)*129 + d] = v.w;
    }
    __syncthreads();

    int w = t >> 6, lane = t & 63, lo = lane & 15, hi = lane >> 4;

    const unsigned short* arow = Ob + ((size_t)(b*512 + n0 + w*16 + lo))*128;
    bf16x8 af[4];
    #pragma unroll
    for (int kc = 0; kc < 4; kc++)
        af[kc] = *(const bf16x8*)(arow + kc*32 + hi*8);

    const f32x4 zero = {0.f, 0.f, 0.f, 0.f};
    for (int nt = 0; nt < 8; nt++) {
        f32x4 acc = zero;
        #pragma unroll
        for (int kc = 0; kc < 4; kc++) {
            bf16x8 bf = *(const bf16x8*)(owS + (nt*16 + lo)*136 + kc*32 + hi*8);
            acc = __builtin_amdgcn_mfma_f32_16x16x32_bf16(af[kc], bf, acc, 0, 0, 0);
        }
        int c = nt*16 + lo;
        #pragma unroll
        for (int jj = 0; jj < 4; jj++) {
            int nl = w*16 + hi*4 + jj;
            xs[nl*129 + c] += a1s[c] * acc[jj];
        }
    }
    __syncthreads();

    {
        int row = t >> 2, sub = t & 3;
        float s = 0.f, ss = 0.f;
        const float* xr = &xs[row*129 + sub*32];
        #pragma unroll
        for (int i = 0; i < 32; i++) { float v = xr[i]; s += v; ss += v*v; }
        s += __shfl_xor(s, 1); ss += __shfl_xor(ss, 1);
        s += __shfl_xor(s, 2); ss += __shfl_xor(ss, 2);
        float mean = s * (1.0f/128.0f);
        float var = (ss - 128.0f*mean*mean) * (1.0f/127.0f);
        var = var < 0.f ? 0.f : var;
        float sd = sqrtf(var);
        mean_s[row] = mean;
        rstd_s[row] = (sd == 0.f) ? 1.f : 1.f/sd;
    }
    __syncthreads();

    float* outb = outp + (size_t)b*65536 + n0;
    for (int idx = t; idx < 2048; idx += 256) {
        int d = idx >> 4, j4 = (idx & 15)*4;
        float4 o;
        {
            float v = xs[(j4+0)*129 + d];
            o.x = v + a2s[d]*(g2s[d]*((v - mean_s[j4+0])*rstd_s[j4+0]) + b2s[d]);
        }
        {
            float v = xs[(j4+1)*129 + d];
            o.y = v + a2s[d]*(g2s[d]*((v - mean_s[j4+1])*rstd_s[j4+1]) + b2s[d]);
        }
        {
            float v = xs[(j4+2)*129 + d];
            o.z = v + a2s[d]*(g2s[d]*((v - mean_s[j4+2])*rstd_s[j4+2]) + b2s[d]);
        }
        {
            float v = xs[(j4+3)*129 + d];
            o.w = v + a2s[d]*(g2s[d]*((v - mean_s[j4+3])*rstd_s[j4+3]) + b2s[d]);
        }
        *(float4*)(outb + (size_t)d*512 + j4) = o;
    }
}

extern "C" void kernel_launch(void* const* d_in, const int* in_sizes, int n_in,
                              void* d_out, int out_size, void* d_ws, size_t ws_size,
                              hipStream_t stream) {
    const float* latent = (const float*)d_in[0];
    const float* nodes  = (const float*)d_in[1];
    const float* tv     = (const float*)d_in[2];
    const float* qw     = (const float*)d_in[3];
    const float* kw     = (const float*)d_in[4];
    const float* vw     = (const float*)d_in[5];
    const float* qb     = (const float*)d_in[6];
    const float* kb     = (const float*)d_in[7];
    const float* vb     = (const float*)d_in[8];
    const float* owp    = (const float*)d_in[9];

    const float* mw[24];
    for (int i = 0; i < 24; i++) mw[i] = (const float*)d_in[10 + i];

    char* wsb = (char*)d_ws;
    unsigned short* Qb  = (unsigned short*)(wsb);
    unsigned short* Kb  = (unsigned short*)(wsb + 8388608);
    unsigned short* Vtb = (unsigned short*)(wsb + 16777216);
    unsigned short* Ob  = (unsigned short*)(wsb + 25165824);
    float* mods         = (float*)(wsb + 33554432);
    unsigned short* cT  = (unsigned short*)(wsb + 33751040);
    unsigned short* owT = (unsigned short*)(wsb + 33849344);

    float* outp = (float*)d_out;

    k_cond<<<dim3(NB*4 + 256), dim3(128), 0, stream>>>(
        nodes, tv,
        mw[0], mw[1], mw[2], mw[3], mw[4], mw[5],
        mw[6], mw[7], mw[8], mw[9], mw[10], mw[11],
        mw[12], mw[13], mw[14], mw[15], mw[16], mw[17],
        mw[18], mw[19], mw[20], mw[21], mw[22], mw[23],
        mods,
        qw, kw, vw, owp, cT, owT);

    k_norm_qkv<<<dim3(NB*8), dim3(256), 0, stream>>>(
        latent, mods, cT, qb, kb, vb, Qb, Kb, Vtb);

    k_attn<<<dim3(NB*4*2), dim3(512), 0, stream>>>(Qb, Kb, Vtb, Ob);

    k_out<<<dim3(NB*8), dim3(256), 0, stream>>>(latent, Ob, owT, mods, outp);
}